// Round 1
// baseline (1377.191 us; speedup 1.0000x reference)
//
#include <hip/hip_runtime.h>

#define NB   128
#define NIN  1024
#define NH   1024
#define BETAF 0.95f
#define PIF  3.14159265358979f

// d_out flat layout (elements), return order:
// spk(B*NH), mem_new(B*NH), loss_mean(1), spk_trace_new(B*NH),
// inp_trace_new(B*NIN), current_dW_new(B*NH*NIN), sample_loss_new(B)
#define OFF_SPK    0
#define OFF_MEM    (NB*NH)
#define OFF_LOSS   (2*NB*NH)
#define OFF_SPKTR  (2*NB*NH + 1)
#define OFF_INPTR  (3*NB*NH + 1)
#define OFF_DW     (3*NB*NH + NB*NIN + 1)
#define OFF_SLOSS  (OFF_DW + (size_t)NB*NH*NIN)

// ---------------------------------------------------------------------------
// Kernel 1: inp_trace_new = beta*inp_trace + inp ; init sample_loss_new, loss
// ---------------------------------------------------------------------------
__global__ __launch_bounds__(256) void k_trace(
    const float* __restrict__ inp, const float* __restrict__ inp_trace,
    const float* __restrict__ sample_loss, float* __restrict__ out)
{
    int t = blockIdx.x * 256 + threadIdx.x;
    if (t < NB * NIN)
        out[OFF_INPTR + t] = BETAF * inp_trace[t] + inp[t];
    if (t < NB)
        out[OFF_SLOSS + t] = sample_loss[t];
    if (t == 0)
        out[OFF_LOSS] = 0.0f;
}

// ---------------------------------------------------------------------------
// Kernel 2: cur = inp @ W^T, leaky step, spk, spk_trace, loss atomics.
// One wave (64 lanes) per (b,h). Block = 4 waves = 4 h's, one b.
// fp64 accumulation to minimize threshold-boundary flips vs np reference.
// ---------------------------------------------------------------------------
__global__ __launch_bounds__(256) void k_leaky(
    const float* __restrict__ inp, const float* __restrict__ W,
    const float* __restrict__ mem, const float* __restrict__ spk_trace,
    const float* __restrict__ prev_spk_trace, const int* __restrict__ bf_p,
    float* __restrict__ out)
{
    const int b    = blockIdx.y;
    const int wave = threadIdx.x >> 6;
    const int lane = threadIdx.x & 63;
    const int h    = blockIdx.x * 4 + wave;

    const float* ir = inp + b * NIN;
    const float* wr = W   + h * NIN;

    double acc = 0.0;
    #pragma unroll
    for (int i = 0; i < NIN; i += 64)
        acc += (double)ir[i + lane] * (double)wr[i + lane];

    #pragma unroll
    for (int off = 32; off > 0; off >>= 1)
        acc += __shfl_down(acc, off, 64);

    __shared__ float s_loss[4];
    if (lane == 0) {
        const int idx = b * NH + h;
        float cur = (float)acc;
        float m   = mem[idx];
        float mn  = BETAF * m + cur - (m > 1.0f ? 1.0f : 0.0f);
        float spk = (mn > 1.0f) ? 1.0f : 0.0f;
        out[OFF_SPK   + idx] = spk;
        out[OFF_MEM   + idx] = mn;
        out[OFF_SPKTR + idx] = spk_trace[idx] + spk * 0.01f;
        s_loss[wave] = spk * prev_spk_trace[idx];
    }
    __syncthreads();
    if (threadIdx.x == 0) {
        float bf = (float)(*bf_p);
        float c  = -bf * (s_loss[0] + s_loss[1] + s_loss[2] + s_loss[3]);
        atomicAdd(&out[OFF_SLOSS + b], c);
        atomicAdd(&out[OFF_LOSS], c * (1.0f / NB));
    }
}

// ---------------------------------------------------------------------------
// Kernel 3 (the 1.07 GB streaming kernel):
//   dW_new[b,h,i] = dW[b,h,i] + bf * pre[b,h] * itn[b,i]
// pre recomputed on the fly from mem_new + prev_spk_trace (broadcast L1 hits).
// j = 4t => float4-aligned dW load, (b,h) constant within a group, i%4==0.
// Output region starts at odd element offset -> scalar dword stores.
// ---------------------------------------------------------------------------
__global__ __launch_bounds__(256) void k_dw(
    const float* __restrict__ dW, const float* __restrict__ pst,
    const int* __restrict__ bf_p, float* __restrict__ out)
{
    const float* __restrict__ itn  = out + OFF_INPTR;
    const float* __restrict__ memn = out + OFF_MEM;
    float* __restrict__ od = out + OFF_DW;

    int t = blockIdx.x * 256 + threadIdx.x;   // t in [0, 2^25)
    int j = t << 2;                           // element index, < 2^27
    int b  = j >> 20;                         // NH*NIN = 2^20
    int h  = (j >> 10) & (NH - 1);
    int i  = j & (NIN - 1);
    int bh = (b << 10) + h;

    float mn = memn[bh];
    float x  = mn - 1.0f;
    float px = PIF * x;
    float p  = (float)(*bf_p) * pst[bh] / (PIF * (1.0f + px * px));

    const float* it = itn + (b << 10) + i;
    float4 d = *(const float4*)(dW + j);

    od[j    ] = d.x + p * it[0];
    od[j + 1] = d.y + p * it[1];
    od[j + 2] = d.z + p * it[2];
    od[j + 3] = d.w + p * it[3];
}

extern "C" void kernel_launch(void* const* d_in, const int* in_sizes, int n_in,
                              void* d_out, int out_size, void* d_ws, size_t ws_size,
                              hipStream_t stream)
{
    const float* inp        = (const float*)d_in[0];
    const float* W          = (const float*)d_in[1];
    const float* mem        = (const float*)d_in[2];
    const float* spk_trace  = (const float*)d_in[3];
    const float* inp_trace  = (const float*)d_in[4];
    const float* pst        = (const float*)d_in[5];
    const float* dW         = (const float*)d_in[6];
    const float* sloss      = (const float*)d_in[7];
    const int*   bf_p       = (const int*)  d_in[8];
    float* out = (float*)d_out;

    // 1) traces + output init
    k_trace<<<dim3((NB * NIN) / 256), dim3(256), 0, stream>>>(inp, inp_trace, sloss, out);

    // 2) matmul + leaky step: grid (NH/4, B), 4 waves/block
    k_leaky<<<dim3(NH / 4, NB), dim3(256), 0, stream>>>(
        inp, W, mem, spk_trace, pst, bf_p, out);

    // 3) dW streaming update: 2^25 groups of 4 elements
    k_dw<<<dim3((NB * NH * NIN / 4) / 256), dim3(256), 0, stream>>>(dW, pst, bf_p, out);
}